// Round 2
// baseline (698.744 us; speedup 1.0000x reference)
//
#include <hip/hip_runtime.h>

// Problem constants (fixed by reference setup_inputs):
//   inputs: [8192, 64] f32, rand: [8192, 64] f32
//   capacity = max(ceil(1.25 * 8192 / 64), 4) = 160
#define S 8192
#define E 64
#define CAP 160
#define ROW (E * CAP)                       // 10240 floats per token row
#define NCHUNK (S / 256)                    // 32 chunks of 256 tokens
static constexpr long long COMB = (long long)S * E * CAP;  // 83,886,080

typedef float f32x4 __attribute__((ext_vector_type(4)));

// --- Kernel 1: per-token router (one wave per token) ----------------------
// argmax (lowest-index tiebreak, matching jnp.argmax), softmax prob at the
// argmax = 1/sum(exp(x-max)), and rand value at the argmax column.
__global__ __launch_bounds__(256) void router_kernel(
    const float* __restrict__ x, const float* __restrict__ rnd,
    int* __restrict__ eidx, float* __restrict__ prob, float* __restrict__ rv)
{
    const int token = blockIdx.x * 4 + (threadIdx.x >> 6);
    const int lane  = threadIdx.x & 63;

    const float v = x[token * E + lane];
    const float r = rnd[token * E + lane];

    float m = v; int ai = lane;
    #pragma unroll
    for (int off = 32; off; off >>= 1) {
        float m2 = __shfl_xor(m, off, 64);
        int   i2 = __shfl_xor(ai, off, 64);
        if (m2 > m || (m2 == m && i2 < ai)) { m = m2; ai = i2; }
    }

    float s = expf(v - m);
    #pragma unroll
    for (int off = 32; off; off >>= 1) s += __shfl_xor(s, off, 64);

    const float ra = __shfl(r, ai, 64);

    if (lane == 0) {
        eidx[token] = ai;
        prob[token] = 1.0f / s;
        rv[token]   = ra;
    }
}

// --- Kernel 2: per-chunk expert histogram (32 blocks) ---------------------
__global__ __launch_bounds__(256) void hist_kernel(
    const int* __restrict__ eidx, int* __restrict__ chunk_hist)
{
    __shared__ int h[E];
    const int b = blockIdx.x;
    if (threadIdx.x < E) h[threadIdx.x] = 0;
    __syncthreads();
    atomicAdd(&h[eidx[b * 256 + threadIdx.x]], 1);
    __syncthreads();
    if (threadIdx.x < E) chunk_hist[b * E + threadIdx.x] = h[threadIdx.x];
}

// --- Kernel 3: slot assignment (32 blocks) --------------------------------
// loc[t] = rank of token t among same-expert tokens by index
//        = (prefix over earlier chunks) + (rank within chunk).
// Writes ofs[t] = e*CAP + loc (or -1 if dropped), counts[e].
// Overflow fallback (count > CAP, NOT triggered for this input: max 152)
// reproduces jax.lax.top_k's (rand desc, index asc) selection exactly.
__global__ __launch_bounds__(256) void rank_kernel(
    const int* __restrict__ eidx, const float* __restrict__ rv,
    const int* __restrict__ chunk_hist,
    int* __restrict__ ofs, int* __restrict__ counts_g)
{
    const int b   = blockIdx.x;
    const int tid = threadIdx.x;
    __shared__ int base[E];
    __shared__ int tot[E];
    __shared__ int le[256];

    if (tid < E) {
        int pre = 0, tt = 0;
        for (int c = 0; c < NCHUNK; ++c) {
            const int v = chunk_hist[c * E + tid];
            if (c < b) pre += v;
            tt += v;
        }
        base[tid] = pre; tot[tid] = tt;
        if (b == 0) counts_g[tid] = tt;
    }
    const int t = b * 256 + tid;
    const int e = eidx[t];
    le[tid] = e;
    __syncthreads();

    int rank = 0;
    for (int j = 0; j < tid; ++j) rank += (le[j] == e);
    int loc = base[e] + rank;

    bool kept = true;
    if (tot[e] > CAP) {   // guarded slow path; never taken for this input
        const float rt = rv[t];
        int better = 0;
        for (int j = 0; j < S; ++j)
            if (eidx[j] == e) {
                const float rj = rv[j];
                if (rj > rt || (rj == rt && j < t)) better++;
            }
        kept = (better < CAP);
        if (kept) {
            int l = 0;
            for (int j = 0; j < t; ++j)
                if (eidx[j] == e) {
                    const float rj = rv[j];
                    int bj = 0;
                    for (int k = 0; k < S; ++k)
                        if (eidx[k] == e) {
                            const float rk = rv[k];
                            if (rk > rj || (rk == rj && k < j)) bj++;
                        }
                    if (bj < CAP) l++;
                }
            loc = l;
        }
    }
    ofs[t] = kept ? (e * CAP + loc) : -1;
}

// --- Kernel 4: zero-fill in rocclr fillBufferAligned's shape --------------
// Grid-strided contiguous float4 plain stores, 2048 blocks x 256 threads,
// zero VALU work per store. The rocclr fill kernel with this pattern was
// measured at 6.1-6.35 TB/s on this buffer in this trace; the previous
// fused compare-and-fill (8192 small blocks, 2 streams 335 MB apart,
// 8 cmp/cndmask per 32 B, nontemporal) inferred ~3 TB/s. No runtime API
// call (hipMemsetAsync suspected in the round-1 container failure).
#define FILL_BLOCKS 2048
__global__ __launch_bounds__(256) void fill_zero_kernel(float* __restrict__ out)
{
    f32x4* __restrict__ dst = (f32x4*)out;
    const size_t n4     = (size_t)(2 * COMB) / 4;          // 41,943,040
    const size_t stride = (size_t)FILL_BLOCKS * 256;       // 524,288
    const f32x4 z = {0.0f, 0.0f, 0.0f, 0.0f};
    for (size_t i = (size_t)blockIdx.x * 256 + threadIdx.x; i < n4; i += stride)
        dst[i] = z;                                        // 80 iterations
}

// --- Kernel 5: sparse scatter (after zero-fill on same stream) ------------
// Only 8192 nonzeros in combine_weights, 8192 in sec_mask, plus the
// 64-entry exp_counts tail.
__global__ __launch_bounds__(256) void scatter_kernel(
    const int* __restrict__ ofs, const float* __restrict__ prob,
    const int* __restrict__ counts, float* __restrict__ out)
{
    const int t = blockIdx.x * 256 + threadIdx.x;
    const int o = ofs[t];            // -1 if dropped (never for this input)
    if (o >= 0) {
        out[(size_t)t * ROW + o]                = prob[t];  // combine_weights
        out[(size_t)COMB + (size_t)t * ROW + o] = 1.0f;     // sec_mask
    }
    if (blockIdx.x == 0 && threadIdx.x < E)
        out[2 * (size_t)COMB + threadIdx.x] = (float)counts[threadIdx.x];
}

extern "C" void kernel_launch(void* const* d_in, const int* in_sizes, int n_in,
                              void* d_out, int out_size, void* d_ws, size_t ws_size,
                              hipStream_t stream)
{
    const float* inputs = (const float*)d_in[0];
    const float* rnd    = (const float*)d_in[1];
    float* out = (float*)d_out;

    // workspace layout (all int32/f32, S=8192):
    //   eidx[S] | prob[S] | rv[S] | ofs[S] | chunk_hist[32*64] | counts[64]
    char* w = (char*)d_ws;
    int*   eidx  = (int*)w;                          w += S * 4;
    float* prob  = (float*)w;                        w += S * 4;
    float* rv    = (float*)w;                        w += S * 4;
    int*   ofs   = (int*)w;                          w += S * 4;
    int*   chist = (int*)w;                          w += NCHUNK * E * 4;
    int*   cnts  = (int*)w;

    fill_zero_kernel<<<FILL_BLOCKS, 256, 0, stream>>>(out);
    router_kernel<<<S / 4, 256, 0, stream>>>(inputs, rnd, eidx, prob, rv);
    hist_kernel<<<NCHUNK, 256, 0, stream>>>(eidx, chist);
    rank_kernel<<<NCHUNK, 256, 0, stream>>>(eidx, rv, chist, ofs, cnts);
    scatter_kernel<<<S / 256, 256, 0, stream>>>(ofs, prob, cnts, out);
}

// Round 3
// 680.039 us; speedup vs baseline: 1.0275x; 1.0275x over previous
//
#include <hip/hip_runtime.h>

// Problem constants (fixed by reference setup_inputs):
//   inputs: [8192, 64] f32, rand: [8192, 64] f32
//   capacity = max(ceil(1.25 * 8192 / 64), 4) = 160
#define S 8192
#define E 64
#define CAP 160
#define ROW (E * CAP)                       // 10240 floats per token row
#define NCHUNK (S / 256)                    // 32 chunks of 256 tokens
static constexpr long long COMB = (long long)S * E * CAP;  // 83,886,080

typedef float f32x4 __attribute__((ext_vector_type(4)));

// --- Kernel 1: per-token router (one wave per token) ----------------------
// argmax (lowest-index tiebreak, matching jnp.argmax), softmax prob at the
// argmax = 1/sum(exp(x-max)), and rand value at the argmax column.
__global__ __launch_bounds__(256) void router_kernel(
    const float* __restrict__ x, const float* __restrict__ rnd,
    int* __restrict__ eidx, float* __restrict__ prob, float* __restrict__ rv)
{
    const int token = blockIdx.x * 4 + (threadIdx.x >> 6);
    const int lane  = threadIdx.x & 63;

    const float v = x[token * E + lane];
    const float r = rnd[token * E + lane];

    float m = v; int ai = lane;
    #pragma unroll
    for (int off = 32; off; off >>= 1) {
        float m2 = __shfl_xor(m, off, 64);
        int   i2 = __shfl_xor(ai, off, 64);
        if (m2 > m || (m2 == m && i2 < ai)) { m = m2; ai = i2; }
    }

    float s = expf(v - m);
    #pragma unroll
    for (int off = 32; off; off >>= 1) s += __shfl_xor(s, off, 64);

    const float ra = __shfl(r, ai, 64);

    if (lane == 0) {
        eidx[token] = ai;
        prob[token] = 1.0f / s;
        rv[token]   = ra;
    }
}

// --- Kernel 2: per-chunk expert histogram (32 blocks) ---------------------
__global__ __launch_bounds__(256) void hist_kernel(
    const int* __restrict__ eidx, int* __restrict__ chunk_hist)
{
    __shared__ int h[E];
    const int b = blockIdx.x;
    if (threadIdx.x < E) h[threadIdx.x] = 0;
    __syncthreads();
    atomicAdd(&h[eidx[b * 256 + threadIdx.x]], 1);
    __syncthreads();
    if (threadIdx.x < E) chunk_hist[b * E + threadIdx.x] = h[threadIdx.x];
}

// --- Kernel 3: slot assignment (32 blocks) --------------------------------
// loc[t] = rank of token t among same-expert tokens by index
//        = (prefix over earlier chunks) + (rank within chunk).
// Writes ofs[t] = e*CAP + loc (or -1 if dropped), counts[e].
// Overflow fallback (count > CAP, NOT triggered for this input: max 152)
// reproduces jax.lax.top_k's (rand desc, index asc) selection exactly.
__global__ __launch_bounds__(256) void rank_kernel(
    const int* __restrict__ eidx, const float* __restrict__ rv,
    const int* __restrict__ chunk_hist,
    int* __restrict__ ofs, int* __restrict__ counts_g)
{
    const int b   = blockIdx.x;
    const int tid = threadIdx.x;
    __shared__ int base[E];
    __shared__ int tot[E];
    __shared__ int le[256];

    if (tid < E) {
        int pre = 0, tt = 0;
        for (int c = 0; c < NCHUNK; ++c) {
            const int v = chunk_hist[c * E + tid];
            if (c < b) pre += v;
            tt += v;
        }
        base[tid] = pre; tot[tid] = tt;
        if (b == 0) counts_g[tid] = tt;
    }
    const int t = b * 256 + tid;
    const int e = eidx[t];
    le[tid] = e;
    __syncthreads();

    int rank = 0;
    for (int j = 0; j < tid; ++j) rank += (le[j] == e);
    int loc = base[e] + rank;

    bool kept = true;
    if (tot[e] > CAP) {   // guarded slow path; never taken for this input
        const float rt = rv[t];
        int better = 0;
        for (int j = 0; j < S; ++j)
            if (eidx[j] == e) {
                const float rj = rv[j];
                if (rj > rt || (rj == rt && j < t)) better++;
            }
        kept = (better < CAP);
        if (kept) {
            int l = 0;
            for (int j = 0; j < t; ++j)
                if (eidx[j] == e) {
                    const float rj = rv[j];
                    int bj = 0;
                    for (int k = 0; k < S; ++k)
                        if (eidx[k] == e) {
                            const float rk = rv[k];
                            if (rk > rj || (rk == rj && k < j)) bj++;
                        }
                    if (bj < CAP) l++;
                }
            loc = l;
        }
    }
    ofs[t] = kept ? (e * CAP + loc) : -1;
}

// --- Kernel 4: zero-fill, rocclr-fillBufferAligned-mimic shape ------------
// Evidence (this trace): rocclr's fill = 6.24 TB/s pure-write at VGPR=8,
// VALUBusy 4.9%, Occupancy 10% (~3-4 waves/CU). My previous fills:
//   r0: 8192 blocks, 2 streams 320MB apart + cmp/cndmask, NT   -> 2.97 TB/s
//   r2: 2048 blocks, 8MB-strided grid-stride, plain stores     -> 2.57 TB/s
// Hypothesis: long per-WAVE sequential streams + NT stores + low wave count
// is what reaches 6+ TB/s. Shape here: 256 blocks (1/CU, 4 waves/CU); each
// wave owns a contiguous 640 KiB slice, walked sequentially 1 KiB/iter,
// 8 NT dwordx4 stores unrolled back-to-back; zero per-store VALU work.
// Exact partition: 256 blk x 4 waves x 640 iters x 1 KiB = 640 MiB = 2*COMB.
#define FILL_BLOCKS 256
__global__ __launch_bounds__(256) void fill_zero_kernel(float* __restrict__ out)
{
    f32x4* __restrict__ dst = (f32x4*)out;
    const int wave = threadIdx.x >> 6;   // 0..3
    const int lane = threadIdx.x & 63;
    // float4 index: block slice 163840, wave slice 40960 (= 640 KiB)
    const size_t base = (size_t)blockIdx.x * 163840 + (size_t)wave * 40960 + lane;
    const f32x4 z = {0.0f, 0.0f, 0.0f, 0.0f};
    #pragma unroll 1
    for (int it = 0; it < 640; it += 8) {
        #pragma unroll
        for (int u = 0; u < 8; ++u)
            __builtin_nontemporal_store(z, &dst[base + (size_t)(it + u) * 64]);
    }
}

// --- Kernel 5: sparse scatter (after zero-fill on same stream) ------------
// Only 8192 nonzeros in combine_weights, 8192 in sec_mask, plus the
// 64-entry exp_counts tail.
__global__ __launch_bounds__(256) void scatter_kernel(
    const int* __restrict__ ofs, const float* __restrict__ prob,
    const int* __restrict__ counts, float* __restrict__ out)
{
    const int t = blockIdx.x * 256 + threadIdx.x;
    const int o = ofs[t];            // -1 if dropped (never for this input)
    if (o >= 0) {
        out[(size_t)t * ROW + o]                = prob[t];  // combine_weights
        out[(size_t)COMB + (size_t)t * ROW + o] = 1.0f;     // sec_mask
    }
    if (blockIdx.x == 0 && threadIdx.x < E)
        out[2 * (size_t)COMB + threadIdx.x] = (float)counts[threadIdx.x];
}

extern "C" void kernel_launch(void* const* d_in, const int* in_sizes, int n_in,
                              void* d_out, int out_size, void* d_ws, size_t ws_size,
                              hipStream_t stream)
{
    const float* inputs = (const float*)d_in[0];
    const float* rnd    = (const float*)d_in[1];
    float* out = (float*)d_out;

    // workspace layout (all int32/f32, S=8192):
    //   eidx[S] | prob[S] | rv[S] | ofs[S] | chunk_hist[32*64] | counts[64]
    char* w = (char*)d_ws;
    int*   eidx  = (int*)w;                          w += S * 4;
    float* prob  = (float*)w;                        w += S * 4;
    float* rv    = (float*)w;                        w += S * 4;
    int*   ofs   = (int*)w;                          w += S * 4;
    int*   chist = (int*)w;                          w += NCHUNK * E * 4;
    int*   cnts  = (int*)w;

    fill_zero_kernel<<<FILL_BLOCKS, 256, 0, stream>>>(out);
    router_kernel<<<S / 4, 256, 0, stream>>>(inputs, rnd, eidx, prob, rv);
    hist_kernel<<<NCHUNK, 256, 0, stream>>>(eidx, chist);
    rank_kernel<<<NCHUNK, 256, 0, stream>>>(eidx, rv, chist, ofs, cnts);
    scatter_kernel<<<S / 256, 256, 0, stream>>>(ofs, prob, cnts, out);
}

// Round 4
// 674.356 us; speedup vs baseline: 1.0362x; 1.0084x over previous
//
#include <hip/hip_runtime.h>

// Problem constants (fixed by reference setup_inputs):
//   inputs: [8192, 64] f32, rand: [8192, 64] f32
//   capacity = max(ceil(1.25 * 8192 / 64), 4) = 160
#define S 8192
#define E 64
#define CAP 160
#define ROW (E * CAP)                       // 10240 floats per token row
#define NCHUNK (S / 256)                    // 32 chunks of 256 tokens
static constexpr long long COMB = (long long)S * E * CAP;  // 83,886,080

typedef float f32x4 __attribute__((ext_vector_type(4)));

// --- Kernel 1: per-token router (one wave per token) ----------------------
// argmax (lowest-index tiebreak, matching jnp.argmax), softmax prob at the
// argmax = 1/sum(exp(x-max)), and rand value at the argmax column.
__global__ __launch_bounds__(256) void router_kernel(
    const float* __restrict__ x, const float* __restrict__ rnd,
    int* __restrict__ eidx, float* __restrict__ prob, float* __restrict__ rv)
{
    const int token = blockIdx.x * 4 + (threadIdx.x >> 6);
    const int lane  = threadIdx.x & 63;

    const float v = x[token * E + lane];
    const float r = rnd[token * E + lane];

    float m = v; int ai = lane;
    #pragma unroll
    for (int off = 32; off; off >>= 1) {
        float m2 = __shfl_xor(m, off, 64);
        int   i2 = __shfl_xor(ai, off, 64);
        if (m2 > m || (m2 == m && i2 < ai)) { m = m2; ai = i2; }
    }

    float s = expf(v - m);
    #pragma unroll
    for (int off = 32; off; off >>= 1) s += __shfl_xor(s, off, 64);

    const float ra = __shfl(r, ai, 64);

    if (lane == 0) {
        eidx[token] = ai;
        prob[token] = 1.0f / s;
        rv[token]   = ra;
    }
}

// --- Kernel 2: per-chunk expert histogram (32 blocks) ---------------------
__global__ __launch_bounds__(256) void hist_kernel(
    const int* __restrict__ eidx, int* __restrict__ chunk_hist)
{
    __shared__ int h[E];
    const int b = blockIdx.x;
    if (threadIdx.x < E) h[threadIdx.x] = 0;
    __syncthreads();
    atomicAdd(&h[eidx[b * 256 + threadIdx.x]], 1);
    __syncthreads();
    if (threadIdx.x < E) chunk_hist[b * E + threadIdx.x] = h[threadIdx.x];
}

// --- Kernel 3: slot assignment (32 blocks) --------------------------------
// loc[t] = rank of token t among same-expert tokens by index
//        = (prefix over earlier chunks) + (rank within chunk).
// Writes ofs[t] = e*CAP + loc (or -1 if dropped), counts[e].
// Overflow fallback (count > CAP, NOT triggered for this input: max 152)
// reproduces jax.lax.top_k's (rand desc, index asc) selection exactly.
__global__ __launch_bounds__(256) void rank_kernel(
    const int* __restrict__ eidx, const float* __restrict__ rv,
    const int* __restrict__ chunk_hist,
    int* __restrict__ ofs, int* __restrict__ counts_g)
{
    const int b   = blockIdx.x;
    const int tid = threadIdx.x;
    __shared__ int base[E];
    __shared__ int tot[E];
    __shared__ int le[256];

    if (tid < E) {
        int pre = 0, tt = 0;
        for (int c = 0; c < NCHUNK; ++c) {
            const int v = chunk_hist[c * E + tid];
            if (c < b) pre += v;
            tt += v;
        }
        base[tid] = pre; tot[tid] = tt;
        if (b == 0) counts_g[tid] = tt;
    }
    const int t = b * 256 + tid;
    const int e = eidx[t];
    le[tid] = e;
    __syncthreads();

    int rank = 0;
    for (int j = 0; j < tid; ++j) rank += (le[j] == e);
    int loc = base[e] + rank;

    bool kept = true;
    if (tot[e] > CAP) {   // guarded slow path; never taken for this input
        const float rt = rv[t];
        int better = 0;
        for (int j = 0; j < S; ++j)
            if (eidx[j] == e) {
                const float rj = rv[j];
                if (rj > rt || (rj == rt && j < t)) better++;
            }
        kept = (better < CAP);
        if (kept) {
            int l = 0;
            for (int j = 0; j < t; ++j)
                if (eidx[j] == e) {
                    const float rj = rv[j];
                    int bj = 0;
                    for (int k = 0; k < S; ++k)
                        if (eidx[k] == e) {
                            const float rk = rv[k];
                            if (rk > rj || (rk == rj && k < j)) bj++;
                        }
                    if (bj < CAP) l++;
                }
            loc = l;
        }
    }
    ofs[t] = kept ? (e * CAP + loc) : -1;
}

// --- Kernel 4: zero-fill with STREAMING stores (sc0 sc1 nt) ---------------
// Evidence so far: 3 fill shapes (8192-blk fused NT / 2048-blk grid-stride
// plain / 256-blk wave-sequential NT) ALL land at 2.6-3.0 TB/s, while
// rocclr's fillBufferAligned does 6.3 TB/s (FETCH~0) on the same arena.
// Shape, grid, VALU work, and the `nt` bit alone are eliminated as levers.
// Remaining difference: store cache policy. Plain/nt global stores
// write-allocate in the 4 MiB per-XCD L2; streaming 640 MiB through it
// makes every line allocate->dirty->evict (2x internal line movement ~=
// the observed 2x BW loss). `sc0 sc1 nt` = device-scope, no-allocate
// streaming store (the policy runtime fills use). Same r3 geometry:
// 256 blocks x 4 waves; each wave owns a contiguous 640 KiB slice.
#define FILL_BLOCKS 256
__global__ __launch_bounds__(256) void fill_zero_kernel(float* __restrict__ out)
{
    const int wave = threadIdx.x >> 6;   // 0..3
    const int lane = threadIdx.x & 63;
    // float index of this lane's first float4: (blk*163840 + wave*40960 + lane)*4
    const float* p = out +
        ((size_t)blockIdx.x * 163840 + (size_t)wave * 40960 + (size_t)lane) * 4;
    f32x4 z = {0.0f, 0.0f, 0.0f, 0.0f};
    #pragma unroll 1
    for (int it = 0; it < 640; it += 4) {
        const float* q = p + (size_t)it * 256;   // 4 stores, 1024 B apart per lane
        asm volatile(
            "global_store_dwordx4 %0, %1, off sc0 sc1 nt\n\t"
            "global_store_dwordx4 %0, %1, off offset:1024 sc0 sc1 nt\n\t"
            "global_store_dwordx4 %0, %1, off offset:2048 sc0 sc1 nt\n\t"
            "global_store_dwordx4 %0, %1, off offset:3072 sc0 sc1 nt"
            :: "v"(q), "v"(z) : "memory");
    }
}

// --- Kernel 5: sparse scatter (after zero-fill on same stream) ------------
// Only 8192 nonzeros in combine_weights, 8192 in sec_mask, plus the
// 64-entry exp_counts tail.
__global__ __launch_bounds__(256) void scatter_kernel(
    const int* __restrict__ ofs, const float* __restrict__ prob,
    const int* __restrict__ counts, float* __restrict__ out)
{
    const int t = blockIdx.x * 256 + threadIdx.x;
    const int o = ofs[t];            // -1 if dropped (never for this input)
    if (o >= 0) {
        out[(size_t)t * ROW + o]                = prob[t];  // combine_weights
        out[(size_t)COMB + (size_t)t * ROW + o] = 1.0f;     // sec_mask
    }
    if (blockIdx.x == 0 && threadIdx.x < E)
        out[2 * (size_t)COMB + threadIdx.x] = (float)counts[threadIdx.x];
}

extern "C" void kernel_launch(void* const* d_in, const int* in_sizes, int n_in,
                              void* d_out, int out_size, void* d_ws, size_t ws_size,
                              hipStream_t stream)
{
    const float* inputs = (const float*)d_in[0];
    const float* rnd    = (const float*)d_in[1];
    float* out = (float*)d_out;

    // workspace layout (all int32/f32, S=8192):
    //   eidx[S] | prob[S] | rv[S] | ofs[S] | chunk_hist[32*64] | counts[64]
    char* w = (char*)d_ws;
    int*   eidx  = (int*)w;                          w += S * 4;
    float* prob  = (float*)w;                        w += S * 4;
    float* rv    = (float*)w;                        w += S * 4;
    int*   ofs   = (int*)w;                          w += S * 4;
    int*   chist = (int*)w;                          w += NCHUNK * E * 4;
    int*   cnts  = (int*)w;

    fill_zero_kernel<<<FILL_BLOCKS, 256, 0, stream>>>(out);
    router_kernel<<<S / 4, 256, 0, stream>>>(inputs, rnd, eidx, prob, rv);
    hist_kernel<<<NCHUNK, 256, 0, stream>>>(eidx, chist);
    rank_kernel<<<NCHUNK, 256, 0, stream>>>(eidx, rv, chist, ofs, cnts);
    scatter_kernel<<<S / 256, 256, 0, stream>>>(ofs, prob, cnts, out);
}

// Round 5
// 661.515 us; speedup vs baseline: 1.0563x; 1.0194x over previous
//
#include <hip/hip_runtime.h>

// Problem constants (fixed by reference setup_inputs):
//   inputs: [8192, 64] f32, rand: [8192, 64] f32
//   capacity = max(ceil(1.25 * 8192 / 64), 4) = 160
#define S 8192
#define E 64
#define CAP 160
#define ROW (E * CAP)                       // 10240 floats per token row
#define NCHUNK (S / 256)                    // 32 chunks of 256 tokens
static constexpr long long COMB = (long long)S * E * CAP;  // 83,886,080

typedef float f32x4 __attribute__((ext_vector_type(4)));

// --- Kernel 1: per-token router (one wave per token) ----------------------
// argmax (lowest-index tiebreak, matching jnp.argmax), softmax prob at the
// argmax = 1/sum(exp(x-max)), and rand value at the argmax column.
__global__ __launch_bounds__(256) void router_kernel(
    const float* __restrict__ x, const float* __restrict__ rnd,
    int* __restrict__ eidx, float* __restrict__ prob, float* __restrict__ rv)
{
    const int token = blockIdx.x * 4 + (threadIdx.x >> 6);
    const int lane  = threadIdx.x & 63;

    const float v = x[token * E + lane];
    const float r = rnd[token * E + lane];

    float m = v; int ai = lane;
    #pragma unroll
    for (int off = 32; off; off >>= 1) {
        float m2 = __shfl_xor(m, off, 64);
        int   i2 = __shfl_xor(ai, off, 64);
        if (m2 > m || (m2 == m && i2 < ai)) { m = m2; ai = i2; }
    }

    float s = expf(v - m);
    #pragma unroll
    for (int off = 32; off; off >>= 1) s += __shfl_xor(s, off, 64);

    const float ra = __shfl(r, ai, 64);

    if (lane == 0) {
        eidx[token] = ai;
        prob[token] = 1.0f / s;
        rv[token]   = ra;
    }
}

// --- Kernel 2: per-chunk expert histogram (32 blocks) ---------------------
__global__ __launch_bounds__(256) void hist_kernel(
    const int* __restrict__ eidx, int* __restrict__ chunk_hist)
{
    __shared__ int h[E];
    const int b = blockIdx.x;
    if (threadIdx.x < E) h[threadIdx.x] = 0;
    __syncthreads();
    atomicAdd(&h[eidx[b * 256 + threadIdx.x]], 1);
    __syncthreads();
    if (threadIdx.x < E) chunk_hist[b * E + threadIdx.x] = h[threadIdx.x];
}

// --- Kernel 3: slot assignment (32 blocks) --------------------------------
// loc[t] = rank of token t among same-expert tokens by index
//        = (prefix over earlier chunks) + (rank within chunk).
// Writes ofs[t] = e*CAP + loc (or -1 if dropped), counts[e].
// Overflow fallback (count > CAP, NOT triggered for this input: max 152)
// reproduces jax.lax.top_k's (rand desc, index asc) selection exactly.
__global__ __launch_bounds__(256) void rank_kernel(
    const int* __restrict__ eidx, const float* __restrict__ rv,
    const int* __restrict__ chunk_hist,
    int* __restrict__ ofs, int* __restrict__ counts_g)
{
    const int b   = blockIdx.x;
    const int tid = threadIdx.x;
    __shared__ int base[E];
    __shared__ int tot[E];
    __shared__ int le[256];

    if (tid < E) {
        int pre = 0, tt = 0;
        for (int c = 0; c < NCHUNK; ++c) {
            const int v = chunk_hist[c * E + tid];
            if (c < b) pre += v;
            tt += v;
        }
        base[tid] = pre; tot[tid] = tt;
        if (b == 0) counts_g[tid] = tt;
    }
    const int t = b * 256 + tid;
    const int e = eidx[t];
    le[tid] = e;
    __syncthreads();

    int rank = 0;
    for (int j = 0; j < tid; ++j) rank += (le[j] == e);
    int loc = base[e] + rank;

    bool kept = true;
    if (tot[e] > CAP) {   // guarded slow path; never taken for this input
        const float rt = rv[t];
        int better = 0;
        for (int j = 0; j < S; ++j)
            if (eidx[j] == e) {
                const float rj = rv[j];
                if (rj > rt || (rj == rt && j < t)) better++;
            }
        kept = (better < CAP);
        if (kept) {
            int l = 0;
            for (int j = 0; j < t; ++j)
                if (eidx[j] == e) {
                    const float rj = rv[j];
                    int bj = 0;
                    for (int k = 0; k < S; ++k)
                        if (eidx[k] == e) {
                            const float rk = rv[k];
                            if (rk > rj || (rk == rj && k < j)) bj++;
                        }
                    if (bj < CAP) l++;
                }
            loc = l;
        }
    }
    ofs[t] = kept ? (e * CAP + loc) : -1;
}

// --- Kernel 4: fused zero-fill + scatter, STREAMING stores ----------------
// Model B (r4 post-mortem): the 2.68 GB / 425 us fillBufferAligned is a
// ~4x-output workspace poison; the OUTPUT's own poison (~106 us) is a
// separate dispatch below the profiler's top-5 cutoff. Under that model
// this fused kernel's history reads: r0 structure = 129 us (5.2 TB/s),
// the best of all four fill variants — more blocks -> more waves -> more
// outstanding stores. This round keeps the r0 structure and applies the
// one untried lever on it: sc0 sc1 nt streaming-store policy (what the
// 6.3 TB/s rocclr fill uses) instead of plain nontemporal stores, to
// avoid L2 write-allocate churn (640 MB through 32 MB of L2).
// One block per token row; every output byte written exactly once:
//   combine_weights[t,:,:] (10240 f32, prob at column ofs[t]),
//   sec_mask[t,:,:]        (10240 f32, 1.0 at column ofs[t]),
//   block 0 writes exp_counts[64].
__global__ __launch_bounds__(256) void fill_scatter_kernel(
    const int* __restrict__ ofs, const float* __restrict__ prob,
    const int* __restrict__ counts, float* __restrict__ out)
{
    const int t   = blockIdx.x;
    const int tid = threadIdx.x;
    const int o   = ofs[t];      // wave-uniform L1 broadcast
    const float v = prob[t];

    float* __restrict__ dst0 = out + (size_t)t * ROW;
    float* __restrict__ dst1 = out + (size_t)COMB + (size_t)t * ROW;

    #pragma unroll
    for (int k = 0; k < ROW / 4 / 256; ++k) {   // 10 iterations
        const int c4  = k * 256 + tid;
        const int col = c4 * 4;
        f32x4 z0, z1;
        z0.x = (o == col + 0) ? v : 0.0f;  z1.x = (o == col + 0) ? 1.0f : 0.0f;
        z0.y = (o == col + 1) ? v : 0.0f;  z1.y = (o == col + 1) ? 1.0f : 0.0f;
        z0.z = (o == col + 2) ? v : 0.0f;  z1.z = (o == col + 2) ? 1.0f : 0.0f;
        z0.w = (o == col + 3) ? v : 0.0f;  z1.w = (o == col + 3) ? 1.0f : 0.0f;
        const float* a0 = dst0 + (size_t)c4 * 4;
        const float* a1 = dst1 + (size_t)c4 * 4;
        asm volatile(
            "global_store_dwordx4 %0, %2, off sc0 sc1 nt\n\t"
            "global_store_dwordx4 %1, %3, off sc0 sc1 nt"
            :: "v"(a0), "v"(a1), "v"(z0), "v"(z1) : "memory");
    }

    if (t == 0 && tid < E)
        out[2 * (size_t)COMB + tid] = (float)counts[tid];
}

extern "C" void kernel_launch(void* const* d_in, const int* in_sizes, int n_in,
                              void* d_out, int out_size, void* d_ws, size_t ws_size,
                              hipStream_t stream)
{
    const float* inputs = (const float*)d_in[0];
    const float* rnd    = (const float*)d_in[1];
    float* out = (float*)d_out;

    // workspace layout (all int32/f32, S=8192):
    //   eidx[S] | prob[S] | rv[S] | ofs[S] | chunk_hist[32*64] | counts[64]
    char* w = (char*)d_ws;
    int*   eidx  = (int*)w;                          w += S * 4;
    float* prob  = (float*)w;                        w += S * 4;
    float* rv    = (float*)w;                        w += S * 4;
    int*   ofs   = (int*)w;                          w += S * 4;
    int*   chist = (int*)w;                          w += NCHUNK * E * 4;
    int*   cnts  = (int*)w;

    router_kernel<<<S / 4, 256, 0, stream>>>(inputs, rnd, eidx, prob, rv);
    hist_kernel<<<NCHUNK, 256, 0, stream>>>(eidx, chist);
    rank_kernel<<<NCHUNK, 256, 0, stream>>>(eidx, rv, chist, ofs, cnts);
    fill_scatter_kernel<<<S, 256, 0, stream>>>(ofs, prob, cnts, out);
}